// Round 4
// baseline (319.243 us; speedup 1.0000x reference)
//
#include <hip/hip_runtime.h>
#include <hip/hip_bf16.h>

// 2-layer GCN (PyG GCNConv) on MI355X.
// R4: bf16 g-tables + multi-edge-per-load gather.
//   - g1/g2 stored as packed bf16 (GEMMs stay fp32 internally, t1 stays fp32):
//     halves gather bytes/edge, doubles L2 coverage of the table.
//   - agg kernels: lane loads uint = 2 bf16 feats; half-wave (agg1) / quarter-
//     wave (agg2) covers one row, so each load instruction fetches 2 (agg1) or
//     4 (agg2) edges. Final cross-group combine via __shfl_xor. 4-deep unroll
//     -> 8 edges in flight per wave (was 4 rows, fp32).
//
// Pipeline: hist -> scan -> partition -> per-bucket CSR fill (+dinv) ->
//           gemm1 -> agg1(relu) -> gemm2 -> agg2.

#define IN_DIM 128
#define HID_DIM 64
#define OUT_DIM 32
#define BSHIFT 8
#define BSIZE 256
#define BMASK 255
#define PEB 16384  // edges per partition block

__device__ inline unsigned pack_bf16x2(float a, float b) {
    unsigned ua = __float_as_uint(a), ub = __float_as_uint(b);
    unsigned ra = (ua + 0x7fffu + ((ua >> 16) & 1u)) >> 16;        // RNE
    unsigned rb = (ub + 0x7fffu + ((ub >> 16) & 1u)) & 0xffff0000u;
    return (ra & 0xffffu) | rb;
}
#define BF_LO(w) __uint_as_float((w) << 16)
#define BF_HI(w) __uint_as_float((w) & 0xffff0000u)

// ---------------------------------------------------------------- pass 1: bucket histogram
__global__ __launch_bounds__(256) void k_hist(const int* __restrict__ dst, int E,
                                              int* __restrict__ mat, int B, int nPB) {
    __shared__ int cnt[512];
    int t = threadIdx.x;
    for (int b = t; b < B; b += 256) cnt[b] = 0;
    __syncthreads();
    int base = blockIdx.x * PEB;
#pragma unroll 8
    for (int i = 0; i < PEB / 256; ++i) {
        int e = base + i * 256 + t;
        if (e < E) atomicAdd(&cnt[dst[e] >> BSHIFT], 1);
    }
    __syncthreads();
    for (int b = t; b < B; b += 256) mat[b * nPB + blockIdx.x] = cnt[b];
}

// ---------------------------------------------------------------- scan (2-level)
__global__ void k_chunk_sums(const int* __restrict__ arr, int M, int* __restrict__ sums) {
    __shared__ int sdata[256];
    int t = threadIdx.x;
    int base = blockIdx.x * 1024 + t * 4;
    int s = 0;
#pragma unroll
    for (int i = 0; i < 4; ++i) {
        int idx = base + i;
        if (idx < M) s += arr[idx];
    }
    sdata[t] = s;
    __syncthreads();
    for (int off = 128; off > 0; off >>= 1) {
        if (t < off) sdata[t] += sdata[t + off];
        __syncthreads();
    }
    if (t == 0) sums[blockIdx.x] = sdata[0];
}

__global__ void k_scan_sums(int* __restrict__ sums, int nchunks) {
    __shared__ int buf[1024];
    int t = threadIdx.x;  // 1024 threads
    int v = (t < nchunks) ? sums[t] : 0;
    buf[t] = v;
    __syncthreads();
    for (int off = 1; off < 1024; off <<= 1) {
        int x = (t >= off) ? buf[t - off] : 0;
        __syncthreads();
        buf[t] += x;
        __syncthreads();
    }
    if (t < nchunks) sums[t] = buf[t] - v;  // exclusive
}

__global__ void k_scan_chunks(const int* __restrict__ arr, int M,
                              const int* __restrict__ sums, int* __restrict__ out) {
    __shared__ int tsum[256];
    int t = threadIdx.x;
    int idx0 = blockIdx.x * 1024 + t * 4;
    int v[4];
    int s = 0;
#pragma unroll
    for (int i = 0; i < 4; ++i) {
        int idx = idx0 + i;
        v[i] = (idx < M) ? arr[idx] : 0;
        s += v[i];
    }
    tsum[t] = s;
    __syncthreads();
    int mine = s;
    for (int off = 1; off < 256; off <<= 1) {
        int x = (t >= off) ? tsum[t - off] : 0;
        __syncthreads();
        tsum[t] += x;
        __syncthreads();
    }
    int run = tsum[t] - mine + sums[blockIdx.x];
#pragma unroll
    for (int i = 0; i < 4; ++i) {
        int idx = idx0 + i;
        if (idx < M) out[idx] = run;
        run += v[i];
    }
}

// ---------------------------------------------------------------- pass 2: partition
__global__ __launch_bounds__(256) void k_partition(const int* __restrict__ src,
                                                   const int* __restrict__ dst, int E,
                                                   const int* __restrict__ mats,
                                                   unsigned* __restrict__ packed,
                                                   int B, int nPB) {
    __shared__ int off[512];
    int t = threadIdx.x;
    for (int b = t; b < B; b += 256) off[b] = mats[b * nPB + blockIdx.x];
    __syncthreads();
    int base = blockIdx.x * PEB;
#pragma unroll 8
    for (int i = 0; i < PEB / 256; ++i) {
        int e = base + i * 256 + t;
        if (e < E) {
            int d = dst[e];
            int s = src[e];
            int slot = atomicAdd(&off[d >> BSHIFT], 1);
            packed[slot] = ((unsigned)s << BSHIFT) | (unsigned)(d & BMASK);
        }
    }
}

// ---------------------------------------------------------------- pass 3: per-bucket CSR build
__global__ __launch_bounds__(256) void k_csrfill(const unsigned* __restrict__ packed,
                                                 const int* __restrict__ mats,
                                                 int* __restrict__ colidx,
                                                 int* __restrict__ rowptr,
                                                 float* __restrict__ dinv,
                                                 int N, int E, int B, int nPB) {
    __shared__ int ldeg[256];
    __shared__ int lscan[256];
    __shared__ int sexc[256];
    __shared__ int lfill[256];
    int t = threadIdx.x, bkt = blockIdx.x;
    int base = mats[bkt * nPB];
    int end  = (bkt + 1 < B) ? mats[(bkt + 1) * nPB] : E;
    ldeg[t] = 0;
    __syncthreads();
    for (int e = base + t; e < end; e += 256)
        atomicAdd(&ldeg[packed[e] & BMASK], 1);
    __syncthreads();
    int v = ldeg[t];
    lscan[t] = v;
    __syncthreads();
    for (int off = 1; off < 256; off <<= 1) {
        int x = (t >= off) ? lscan[t - off] : 0;
        __syncthreads();
        lscan[t] += x;
        __syncthreads();
    }
    int exc = lscan[t] - v;
    sexc[t] = exc;
    lfill[t] = 0;
    int node = (bkt << BSHIFT) + t;
    if (node < N) {
        rowptr[node] = base + exc;
        dinv[node] = rsqrtf((float)v + 1.0f);
    }
    if (bkt == B - 1 && t == 0) rowptr[N] = E;
    __syncthreads();
    for (int e = base + t; e < end; e += 256) {
        unsigned w = packed[e];
        int ld = w & BMASK;
        int pos = base + sexc[ld] + atomicAdd(&lfill[ld], 1);
        colidx[pos] = (int)(w >> BSHIFT);
    }
}

// ---------------------------------------------------------------- GEMM1: g1b = bf16((x @ W1) * dinv)
__global__ __launch_bounds__(256) void k_gemm1(const float* __restrict__ x,
                                               const float* __restrict__ W,
                                               const float* __restrict__ dinv,
                                               unsigned* __restrict__ g1b, int N) {
    __shared__ float xs[64 * 128];
    __shared__ float ws[128 * 64];
    int t = threadIdx.x;
    int row0 = blockIdx.x * 64;

    const float4* W4 = (const float4*)W;
    float4* ws4 = (float4*)ws;
#pragma unroll
    for (int i = 0; i < 8; ++i) ws4[t + 256 * i] = W4[t + 256 * i];
#pragma unroll
    for (int i = 0; i < 8; ++i) {
        int l = t + 256 * i;
        int r = l >> 5;
        int c4 = l & 31;
        int row = row0 + r;
        float4 val = make_float4(0.f, 0.f, 0.f, 0.f);
        if (row < N) val = ((const float4*)(x + (size_t)row * IN_DIM))[c4];
        *(float4*)&xs[r * IN_DIM + c4 * 4] = val;
    }
    __syncthreads();

    int tx = t & 15;
    int ty = t >> 4;
    float acc[4][4] = {};
    for (int k = 0; k < 128; k += 4) {
        float a[4][4], b[4][4];
#pragma unroll
        for (int i = 0; i < 4; ++i)
            *(float4*)a[i] = *(const float4*)&xs[(ty * 4 + i) * IN_DIM + k];
#pragma unroll
        for (int kk = 0; kk < 4; ++kk)
            *(float4*)b[kk] = *(const float4*)&ws[(k + kk) * HID_DIM + tx * 4];
#pragma unroll
        for (int i = 0; i < 4; ++i)
#pragma unroll
            for (int kk = 0; kk < 4; ++kk)
#pragma unroll
                for (int j = 0; j < 4; ++j)
                    acc[i][j] += a[i][kk] * b[kk][j];
    }
#pragma unroll
    for (int i = 0; i < 4; ++i) {
        int row = row0 + ty * 4 + i;
        if (row < N) {
            float dv = dinv[row];
            uint2 u;
            u.x = pack_bf16x2(acc[i][0] * dv, acc[i][1] * dv);
            u.y = pack_bf16x2(acc[i][2] * dv, acc[i][3] * dv);
            *(uint2*)&g1b[(size_t)row * 32 + tx * 2] = u;
        }
    }
}

// ---------------------------------------------------------------- GEMM2: g2b = bf16((t1 @ W2) * dinv)
__global__ __launch_bounds__(256) void k_gemm2(const float* __restrict__ t1,
                                               const float* __restrict__ W,
                                               const float* __restrict__ dinv,
                                               unsigned* __restrict__ g2b, int N) {
    __shared__ float xs[64 * 68];
    __shared__ float ws[64 * 32];
    int t = threadIdx.x;
    int row0 = blockIdx.x * 64;

    const float4* W4 = (const float4*)W;
    float4* ws4 = (float4*)ws;
#pragma unroll
    for (int i = 0; i < 2; ++i) ws4[t + 256 * i] = W4[t + 256 * i];
#pragma unroll
    for (int i = 0; i < 4; ++i) {
        int l = t + 256 * i;
        int r = l >> 4;
        int c4 = l & 15;
        int row = row0 + r;
        float4 val = make_float4(0.f, 0.f, 0.f, 0.f);
        if (row < N) val = ((const float4*)(t1 + (size_t)row * HID_DIM))[c4];
        *(float4*)&xs[r * 68 + c4 * 4] = val;
    }
    __syncthreads();

    int tx = t & 7;
    int ty = t >> 3;
    float acc[2][4] = {};
    for (int k = 0; k < 64; k += 4) {
        float a[2][4], b[4][4];
#pragma unroll
        for (int i = 0; i < 2; ++i)
            *(float4*)a[i] = *(const float4*)&xs[(ty * 2 + i) * 68 + k];
#pragma unroll
        for (int kk = 0; kk < 4; ++kk)
            *(float4*)b[kk] = *(const float4*)&ws[(k + kk) * OUT_DIM + tx * 4];
#pragma unroll
        for (int i = 0; i < 2; ++i)
#pragma unroll
            for (int kk = 0; kk < 4; ++kk)
#pragma unroll
                for (int j = 0; j < 4; ++j)
                    acc[i][j] += a[i][kk] * b[kk][j];
    }
#pragma unroll
    for (int i = 0; i < 2; ++i) {
        int row = row0 + ty * 2 + i;
        if (row < N) {
            float dv = dinv[row];
            uint2 u;
            u.x = pack_bf16x2(acc[i][0] * dv, acc[i][1] * dv);
            u.y = pack_bf16x2(acc[i][2] * dv, acc[i][3] * dv);
            *(uint2*)&g2b[(size_t)row * 16 + tx * 2] = u;
        }
    }
}

// ---------------------------------------------------------------- agg layer 1
// One wave per node. Lane = (grp: which edge of a pair, fp: feat pair 0..31).
// Each load instruction fetches 2 edges x 128B bf16 rows; 4-deep unroll = 8
// edges in flight. Cross-half combine via shfl_xor(32).
__global__ __launch_bounds__(256) void k_agg1(const unsigned* __restrict__ g1,
                                              const int* __restrict__ rowptr,
                                              const int* __restrict__ colidx,
                                              const float* __restrict__ dinv,
                                              const float* __restrict__ b1,
                                              float* __restrict__ t1, int N) {
    int d = (blockIdx.x * 256 + threadIdx.x) >> 6;
    if (d >= N) return;
    int lane = threadIdx.x & 63;
    int grp = lane >> 5, fp = lane & 31;
    float a0 = 0.f, a1 = 0.f;
    int beg = rowptr[d], end = rowptr[d + 1];
    int e = beg;
    for (; e + 8 <= end; e += 8) {
        int s0 = colidx[e + grp];
        int s1 = colidx[e + 2 + grp];
        int s2 = colidx[e + 4 + grp];
        int s3 = colidx[e + 6 + grp];
        unsigned w0 = g1[(size_t)s0 * 32 + fp];
        unsigned w1 = g1[(size_t)s1 * 32 + fp];
        unsigned w2 = g1[(size_t)s2 * 32 + fp];
        unsigned w3 = g1[(size_t)s3 * 32 + fp];
        a0 += BF_LO(w0); a1 += BF_HI(w0);
        a0 += BF_LO(w1); a1 += BF_HI(w1);
        a0 += BF_LO(w2); a1 += BF_HI(w2);
        a0 += BF_LO(w3); a1 += BF_HI(w3);
    }
    for (; e + 2 <= end; e += 2) {
        int s = colidx[e + grp];
        unsigned w = g1[(size_t)s * 32 + fp];
        a0 += BF_LO(w); a1 += BF_HI(w);
    }
    if (e < end) {  // one edge left: half 0 only
        int s = colidx[e];
        unsigned w = g1[(size_t)s * 32 + fp];
        if (grp == 0) { a0 += BF_LO(w); a1 += BF_HI(w); }
    }
    a0 += __shfl_xor(a0, 32);
    a1 += __shfl_xor(a1, 32);
    // epilogue: self-loop + dinv*acc + b1, relu; half 0 writes float2 (256B/row)
    unsigned sw = g1[(size_t)d * 32 + fp];
    float dv = dinv[d];
    float2 bb = ((const float2*)b1)[fp];
    float v0 = dv * (a0 + BF_LO(sw)) + bb.x;
    float v1 = dv * (a1 + BF_HI(sw)) + bb.y;
    if (grp == 0) {
        float2 r;
        r.x = v0 > 0.f ? v0 : 0.f;
        r.y = v1 > 0.f ? v1 : 0.f;
        ((float2*)(t1 + (size_t)d * HID_DIM))[fp] = r;
    }
}

// ---------------------------------------------------------------- agg layer 2
// One wave per node. grp = lane>>4 (4 edges per load instruction), fp = feat
// pair 0..15 (32 feats, 64B bf16 rows). Combine via shfl_xor(16)+shfl_xor(32).
__global__ __launch_bounds__(256) void k_agg2(const unsigned* __restrict__ g2,
                                              const int* __restrict__ rowptr,
                                              const int* __restrict__ colidx,
                                              const float* __restrict__ dinv,
                                              const float* __restrict__ b2,
                                              float* __restrict__ out, int N) {
    int d = (blockIdx.x * 256 + threadIdx.x) >> 6;
    if (d >= N) return;
    int lane = threadIdx.x & 63;
    int grp = lane >> 4, fp = lane & 15;
    float a0 = 0.f, a1 = 0.f;
    int beg = rowptr[d], end = rowptr[d + 1];
    int e = beg;
    for (; e + 8 <= end; e += 8) {
        int s0 = colidx[e + grp];
        int s1 = colidx[e + 4 + grp];
        unsigned w0 = g2[(size_t)s0 * 16 + fp];
        unsigned w1 = g2[(size_t)s1 * 16 + fp];
        a0 += BF_LO(w0); a1 += BF_HI(w0);
        a0 += BF_LO(w1); a1 += BF_HI(w1);
    }
    for (; e + 4 <= end; e += 4) {
        int s = colidx[e + grp];
        unsigned w = g2[(size_t)s * 16 + fp];
        a0 += BF_LO(w); a1 += BF_HI(w);
    }
    if (e < end) {  // 1..3 edges left
        int cnt = end - e;
        int s = colidx[(grp < cnt) ? e + grp : e];
        unsigned w = g2[(size_t)s * 16 + fp];
        if (grp < cnt) { a0 += BF_LO(w); a1 += BF_HI(w); }
    }
    a0 += __shfl_xor(a0, 16);
    a0 += __shfl_xor(a0, 32);
    a1 += __shfl_xor(a1, 16);
    a1 += __shfl_xor(a1, 32);
    unsigned sw = g2[(size_t)d * 16 + fp];
    float dv = dinv[d];
    float2 bb = ((const float2*)b2)[fp];
    float v0 = dv * (a0 + BF_LO(sw)) + bb.x;
    float v1 = dv * (a1 + BF_HI(sw)) + bb.y;
    if (grp == 0) {
        float2 r; r.x = v0; r.y = v1;
        ((float2*)(out + (size_t)d * OUT_DIM))[fp] = r;
    }
}

// ---------------------------------------------------------------- launch
extern "C" void kernel_launch(void* const* d_in, const int* in_sizes, int n_in,
                              void* d_out, int out_size, void* d_ws, size_t ws_size,
                              hipStream_t stream) {
    const float* x  = (const float*)d_in[0];
    const int*   ei = (const int*)d_in[1];
    const float* W1 = (const float*)d_in[2];
    const float* b1 = (const float*)d_in[3];
    const float* W2 = (const float*)d_in[4];
    const float* b2 = (const float*)d_in[5];
    float* out = (float*)d_out;

    const int N = in_sizes[0] / IN_DIM;
    const int E = in_sizes[1] / 2;
    const int* src = ei;
    const int* dst = ei + E;

    const int B   = (N + BSIZE - 1) / BSIZE;
    const int nPB = (E + PEB - 1) / PEB;
    const int M   = B * nPB;
    const int nchunks = (M + 1023) / 1024;

    char* p = (char*)d_ws;
    auto alloc = [&](size_t bytes) -> void* {
        void* r = (void*)p;
        p += (bytes + 255) & ~(size_t)255;
        return r;
    };
    int*      mat    = (int*)alloc((size_t)M * 4);
    int*      mats   = (int*)alloc((size_t)M * 4);
    int*      sums   = (int*)alloc((size_t)nchunks * 4);
    unsigned* packed = (unsigned*)alloc((size_t)E * 4);
    int*      colidx = (int*)alloc((size_t)E * 4);
    int*      rowptr = (int*)alloc((size_t)(N + 1) * 4);
    float*    dinv   = (float*)alloc((size_t)N * 4);
    unsigned* g1b    = (unsigned*)alloc((size_t)N * 32 * 4);  // bf16x2 x 32/row
    unsigned* g2b    = (unsigned*)alloc((size_t)N * 16 * 4);  // bf16x2 x 16/row
    float*    t1     = (float*)alloc((size_t)N * HID_DIM * 4);

    k_hist<<<nPB, 256, 0, stream>>>(dst, E, mat, B, nPB);
    k_chunk_sums<<<nchunks, 256, 0, stream>>>(mat, M, sums);
    k_scan_sums<<<1, 1024, 0, stream>>>(sums, nchunks);
    k_scan_chunks<<<nchunks, 256, 0, stream>>>(mat, M, sums, mats);
    k_partition<<<nPB, 256, 0, stream>>>(src, dst, E, mats, packed, B, nPB);
    k_csrfill<<<B, 256, 0, stream>>>(packed, mats, colidx, rowptr, dinv, N, E, B, nPB);

    k_gemm1<<<(N + 63) / 64, 256, 0, stream>>>(x, W1, dinv, g1b, N);
    k_agg1<<<(N + 3) / 4, 256, 0, stream>>>(g1b, rowptr, colidx, dinv, b1, t1, N);
    k_gemm2<<<(N + 63) / 64, 256, 0, stream>>>(t1, W2, dinv, g2b, N);
    k_agg2<<<(N + 3) / 4, 256, 0, stream>>>(g2b, rowptr, colidx, dinv, b2, out, N);
}

// Round 5
// 296.289 us; speedup vs baseline: 1.0775x; 1.0775x over previous
//
#include <hip/hip_runtime.h>
#include <hip/hip_bf16.h>

// 2-layer GCN (PyG GCNConv) on MI355X.
// R5: PEB back to 8192 (R4's 16384 halved hist/partition TLP, -20us);
//     GEMM2 fused into agg1 (W2 in LDS, per-wave row dot, kills t1 traffic
//     and one dispatch); deeper gather unroll (agg1: 16 edges in flight).
//
// Pipeline: hist -> scan -> partition -> per-bucket CSR fill (+dinv) ->
//           gemm1 -> agg1f (gather + relu + @W2 * dinv -> g2b bf16) -> agg2.

#define IN_DIM 128
#define HID_DIM 64
#define OUT_DIM 32
#define BSHIFT 8
#define BSIZE 256
#define BMASK 255
#define PEB 8192   // edges per partition block

__device__ inline unsigned pack_bf16x2(float a, float b) {
    unsigned ua = __float_as_uint(a), ub = __float_as_uint(b);
    unsigned ra = (ua + 0x7fffu + ((ua >> 16) & 1u)) >> 16;        // RNE
    unsigned rb = (ub + 0x7fffu + ((ub >> 16) & 1u)) & 0xffff0000u;
    return (ra & 0xffffu) | rb;
}
__device__ inline unsigned short f2bf(float f) {
    unsigned u = __float_as_uint(f);
    return (unsigned short)((u + 0x7fffu + ((u >> 16) & 1u)) >> 16);
}
#define BF_LO(w) __uint_as_float((w) << 16)
#define BF_HI(w) __uint_as_float((w) & 0xffff0000u)

// ---------------------------------------------------------------- pass 1: bucket histogram
__global__ __launch_bounds__(256) void k_hist(const int* __restrict__ dst, int E,
                                              int* __restrict__ mat, int B, int nPB) {
    __shared__ int cnt[512];
    int t = threadIdx.x;
    for (int b = t; b < B; b += 256) cnt[b] = 0;
    __syncthreads();
    int base = blockIdx.x * PEB;
#pragma unroll
    for (int i = 0; i < PEB / 256; ++i) {
        int e = base + i * 256 + t;
        if (e < E) atomicAdd(&cnt[dst[e] >> BSHIFT], 1);
    }
    __syncthreads();
    for (int b = t; b < B; b += 256) mat[b * nPB + blockIdx.x] = cnt[b];
}

// ---------------------------------------------------------------- scan (2-level)
__global__ void k_chunk_sums(const int* __restrict__ arr, int M, int* __restrict__ sums) {
    __shared__ int sdata[256];
    int t = threadIdx.x;
    int base = blockIdx.x * 1024 + t * 4;
    int s = 0;
#pragma unroll
    for (int i = 0; i < 4; ++i) {
        int idx = base + i;
        if (idx < M) s += arr[idx];
    }
    sdata[t] = s;
    __syncthreads();
    for (int off = 128; off > 0; off >>= 1) {
        if (t < off) sdata[t] += sdata[t + off];
        __syncthreads();
    }
    if (t == 0) sums[blockIdx.x] = sdata[0];
}

__global__ void k_scan_sums(int* __restrict__ sums, int nchunks) {
    __shared__ int buf[1024];
    int t = threadIdx.x;  // 1024 threads
    int v = (t < nchunks) ? sums[t] : 0;
    buf[t] = v;
    __syncthreads();
    for (int off = 1; off < 1024; off <<= 1) {
        int x = (t >= off) ? buf[t - off] : 0;
        __syncthreads();
        buf[t] += x;
        __syncthreads();
    }
    if (t < nchunks) sums[t] = buf[t] - v;  // exclusive
}

__global__ void k_scan_chunks(const int* __restrict__ arr, int M,
                              const int* __restrict__ sums, int* __restrict__ out) {
    __shared__ int tsum[256];
    int t = threadIdx.x;
    int idx0 = blockIdx.x * 1024 + t * 4;
    int v[4];
    int s = 0;
#pragma unroll
    for (int i = 0; i < 4; ++i) {
        int idx = idx0 + i;
        v[i] = (idx < M) ? arr[idx] : 0;
        s += v[i];
    }
    tsum[t] = s;
    __syncthreads();
    int mine = s;
    for (int off = 1; off < 256; off <<= 1) {
        int x = (t >= off) ? tsum[t - off] : 0;
        __syncthreads();
        tsum[t] += x;
        __syncthreads();
    }
    int run = tsum[t] - mine + sums[blockIdx.x];
#pragma unroll
    for (int i = 0; i < 4; ++i) {
        int idx = idx0 + i;
        if (idx < M) out[idx] = run;
        run += v[i];
    }
}

// ---------------------------------------------------------------- pass 2: partition
__global__ __launch_bounds__(256) void k_partition(const int* __restrict__ src,
                                                   const int* __restrict__ dst, int E,
                                                   const int* __restrict__ mats,
                                                   unsigned* __restrict__ packed,
                                                   int B, int nPB) {
    __shared__ int off[512];
    int t = threadIdx.x;
    for (int b = t; b < B; b += 256) off[b] = mats[b * nPB + blockIdx.x];
    __syncthreads();
    int base = blockIdx.x * PEB;
#pragma unroll
    for (int i = 0; i < PEB / 256; ++i) {
        int e = base + i * 256 + t;
        if (e < E) {
            int d = dst[e];
            int s = src[e];
            int slot = atomicAdd(&off[d >> BSHIFT], 1);
            packed[slot] = ((unsigned)s << BSHIFT) | (unsigned)(d & BMASK);
        }
    }
}

// ---------------------------------------------------------------- pass 3: per-bucket CSR build
__global__ __launch_bounds__(256) void k_csrfill(const unsigned* __restrict__ packed,
                                                 const int* __restrict__ mats,
                                                 int* __restrict__ colidx,
                                                 int* __restrict__ rowptr,
                                                 float* __restrict__ dinv,
                                                 int N, int E, int B, int nPB) {
    __shared__ int ldeg[256];
    __shared__ int lscan[256];
    __shared__ int sexc[256];
    __shared__ int lfill[256];
    int t = threadIdx.x, bkt = blockIdx.x;
    int base = mats[bkt * nPB];
    int end  = (bkt + 1 < B) ? mats[(bkt + 1) * nPB] : E;
    ldeg[t] = 0;
    __syncthreads();
    for (int e = base + t; e < end; e += 256)
        atomicAdd(&ldeg[packed[e] & BMASK], 1);
    __syncthreads();
    int v = ldeg[t];
    lscan[t] = v;
    __syncthreads();
    for (int off = 1; off < 256; off <<= 1) {
        int x = (t >= off) ? lscan[t - off] : 0;
        __syncthreads();
        lscan[t] += x;
        __syncthreads();
    }
    int exc = lscan[t] - v;
    sexc[t] = exc;
    lfill[t] = 0;
    int node = (bkt << BSHIFT) + t;
    if (node < N) {
        rowptr[node] = base + exc;
        dinv[node] = rsqrtf((float)v + 1.0f);
    }
    if (bkt == B - 1 && t == 0) rowptr[N] = E;
    __syncthreads();
    for (int e = base + t; e < end; e += 256) {
        unsigned w = packed[e];
        int ld = w & BMASK;
        int pos = base + sexc[ld] + atomicAdd(&lfill[ld], 1);
        colidx[pos] = (int)(w >> BSHIFT);
    }
}

// ---------------------------------------------------------------- GEMM1: g1b = bf16((x @ W1) * dinv)
__global__ __launch_bounds__(256) void k_gemm1(const float* __restrict__ x,
                                               const float* __restrict__ W,
                                               const float* __restrict__ dinv,
                                               unsigned* __restrict__ g1b, int N) {
    __shared__ float xs[64 * 128];
    __shared__ float ws[128 * 64];
    int t = threadIdx.x;
    int row0 = blockIdx.x * 64;

    const float4* W4 = (const float4*)W;
    float4* ws4 = (float4*)ws;
#pragma unroll
    for (int i = 0; i < 8; ++i) ws4[t + 256 * i] = W4[t + 256 * i];
#pragma unroll
    for (int i = 0; i < 8; ++i) {
        int l = t + 256 * i;
        int r = l >> 5;
        int c4 = l & 31;
        int row = row0 + r;
        float4 val = make_float4(0.f, 0.f, 0.f, 0.f);
        if (row < N) val = ((const float4*)(x + (size_t)row * IN_DIM))[c4];
        *(float4*)&xs[r * IN_DIM + c4 * 4] = val;
    }
    __syncthreads();

    int tx = t & 15;
    int ty = t >> 4;
    float acc[4][4] = {};
    for (int k = 0; k < 128; k += 4) {
        float a[4][4], b[4][4];
#pragma unroll
        for (int i = 0; i < 4; ++i)
            *(float4*)a[i] = *(const float4*)&xs[(ty * 4 + i) * IN_DIM + k];
#pragma unroll
        for (int kk = 0; kk < 4; ++kk)
            *(float4*)b[kk] = *(const float4*)&ws[(k + kk) * HID_DIM + tx * 4];
#pragma unroll
        for (int i = 0; i < 4; ++i)
#pragma unroll
            for (int kk = 0; kk < 4; ++kk)
#pragma unroll
                for (int j = 0; j < 4; ++j)
                    acc[i][j] += a[i][kk] * b[kk][j];
    }
#pragma unroll
    for (int i = 0; i < 4; ++i) {
        int row = row0 + ty * 4 + i;
        if (row < N) {
            float dv = dinv[row];
            uint2 u;
            u.x = pack_bf16x2(acc[i][0] * dv, acc[i][1] * dv);
            u.y = pack_bf16x2(acc[i][2] * dv, acc[i][3] * dv);
            *(uint2*)&g1b[(size_t)row * 32 + tx * 2] = u;
        }
    }
}

// ---------------------------------------------------------------- agg1 + fused GEMM2
// One wave per node. Gather phase: lane=(grp,fp), 8 loads/iter = 16 edges in
// flight. Epilogue: relu row -> per-wave LDS buffer -> each lane computes one
// output feature (32-MAC half-dot + shfl_xor(32)), scales by dinv, packs bf16.
// Kills the separate gemm2 dispatch and all t1 global traffic.
__global__ __launch_bounds__(256) void k_agg1f(const unsigned* __restrict__ g1,
                                               const int* __restrict__ rowptr,
                                               const int* __restrict__ colidx,
                                               const float* __restrict__ dinv,
                                               const float* __restrict__ b1,
                                               const float* __restrict__ W2,
                                               unsigned short* __restrict__ g2b, int N) {
    __shared__ float W2s[HID_DIM * OUT_DIM];  // 8KB, [k][j]
    __shared__ float rowb[4][HID_DIM];        // per-wave relu row
    int t = threadIdx.x;
#pragma unroll
    for (int i = 0; i < 8; ++i) W2s[t + 256 * i] = W2[t + 256 * i];
    __syncthreads();

    int dd = (blockIdx.x * 256 + t) >> 6;
    bool live = dd < N;
    int d = live ? dd : N - 1;
    int lane = t & 63, grp = lane >> 5, fp = lane & 31, w = t >> 6;

    float a0 = 0.f, a1 = 0.f;
    int beg = rowptr[d], end = rowptr[d + 1];
    int e = beg;
    for (; e + 16 <= end; e += 16) {
        int s0 = colidx[e + grp],      s1 = colidx[e + 2 + grp];
        int s2 = colidx[e + 4 + grp],  s3 = colidx[e + 6 + grp];
        int s4 = colidx[e + 8 + grp],  s5 = colidx[e + 10 + grp];
        int s6 = colidx[e + 12 + grp], s7 = colidx[e + 14 + grp];
        unsigned w0 = g1[(size_t)s0 * 32 + fp];
        unsigned w1 = g1[(size_t)s1 * 32 + fp];
        unsigned w2 = g1[(size_t)s2 * 32 + fp];
        unsigned w3 = g1[(size_t)s3 * 32 + fp];
        unsigned w4 = g1[(size_t)s4 * 32 + fp];
        unsigned w5 = g1[(size_t)s5 * 32 + fp];
        unsigned w6 = g1[(size_t)s6 * 32 + fp];
        unsigned w7 = g1[(size_t)s7 * 32 + fp];
        a0 += BF_LO(w0); a1 += BF_HI(w0);
        a0 += BF_LO(w1); a1 += BF_HI(w1);
        a0 += BF_LO(w2); a1 += BF_HI(w2);
        a0 += BF_LO(w3); a1 += BF_HI(w3);
        a0 += BF_LO(w4); a1 += BF_HI(w4);
        a0 += BF_LO(w5); a1 += BF_HI(w5);
        a0 += BF_LO(w6); a1 += BF_HI(w6);
        a0 += BF_LO(w7); a1 += BF_HI(w7);
    }
    for (; e + 2 <= end; e += 2) {
        int s = colidx[e + grp];
        unsigned ww = g1[(size_t)s * 32 + fp];
        a0 += BF_LO(ww); a1 += BF_HI(ww);
    }
    if (e < end) {  // one edge left: half 0 only
        int s = colidx[e];
        unsigned ww = g1[(size_t)s * 32 + fp];
        if (grp == 0) { a0 += BF_LO(ww); a1 += BF_HI(ww); }
    }
    a0 += __shfl_xor(a0, 32);
    a1 += __shfl_xor(a1, 32);

    unsigned sw = g1[(size_t)d * 32 + fp];
    float dv = dinv[d];
    float2 bb = ((const float2*)b1)[fp];
    float v0 = dv * (a0 + BF_LO(sw)) + bb.x;
    float v1 = dv * (a1 + BF_HI(sw)) + bb.y;
    v0 = v0 > 0.f ? v0 : 0.f;
    v1 = v1 > 0.f ? v1 : 0.f;
    if (grp == 0) {
        rowb[w][2 * fp] = v0;
        rowb[w][2 * fp + 1] = v1;
    }
    __syncthreads();  // all waves' rowb written (block-wide, conservative)

    // fused GEMM2: out feat j = lane&31, half h = grp covers k in [32h,32h+32)
    int j = fp, h = grp;
    float acc = 0.f;
#pragma unroll
    for (int k = 0; k < 32; ++k) {
        float rv = rowb[w][h * 32 + k];           // broadcast within half
        acc += rv * W2s[(h * 32 + k) * OUT_DIM + j];
    }
    acc += __shfl_xor(acc, 32);
    if (live && grp == 0)
        g2b[(size_t)dd * 32 + j] = f2bf(acc * dv);
}

// ---------------------------------------------------------------- agg layer 2
// One wave per node. grp = lane>>4 (4 edges per load instruction), fp = feat
// pair 0..15. 4 loads/iter = 16 edges in flight.
__global__ __launch_bounds__(256) void k_agg2(const unsigned* __restrict__ g2,
                                              const int* __restrict__ rowptr,
                                              const int* __restrict__ colidx,
                                              const float* __restrict__ dinv,
                                              const float* __restrict__ b2,
                                              float* __restrict__ out, int N) {
    int d = (blockIdx.x * 256 + threadIdx.x) >> 6;
    if (d >= N) return;
    int lane = threadIdx.x & 63;
    int grp = lane >> 4, fp = lane & 15;
    float a0 = 0.f, a1 = 0.f;
    int beg = rowptr[d], end = rowptr[d + 1];
    int e = beg;
    for (; e + 16 <= end; e += 16) {
        int s0 = colidx[e + grp];
        int s1 = colidx[e + 4 + grp];
        int s2 = colidx[e + 8 + grp];
        int s3 = colidx[e + 12 + grp];
        unsigned w0 = g2[(size_t)s0 * 16 + fp];
        unsigned w1 = g2[(size_t)s1 * 16 + fp];
        unsigned w2 = g2[(size_t)s2 * 16 + fp];
        unsigned w3 = g2[(size_t)s3 * 16 + fp];
        a0 += BF_LO(w0); a1 += BF_HI(w0);
        a0 += BF_LO(w1); a1 += BF_HI(w1);
        a0 += BF_LO(w2); a1 += BF_HI(w2);
        a0 += BF_LO(w3); a1 += BF_HI(w3);
    }
    for (; e + 4 <= end; e += 4) {
        int s = colidx[e + grp];
        unsigned w = g2[(size_t)s * 16 + fp];
        a0 += BF_LO(w); a1 += BF_HI(w);
    }
    if (e < end) {  // 1..3 edges left
        int cnt = end - e;
        int s = colidx[(grp < cnt) ? e + grp : e];
        unsigned w = g2[(size_t)s * 16 + fp];
        if (grp < cnt) { a0 += BF_LO(w); a1 += BF_HI(w); }
    }
    a0 += __shfl_xor(a0, 16);
    a0 += __shfl_xor(a0, 32);
    a1 += __shfl_xor(a1, 16);
    a1 += __shfl_xor(a1, 32);
    unsigned sw = g2[(size_t)d * 16 + fp];
    float dv = dinv[d];
    float2 bb = ((const float2*)b2)[fp];
    float v0 = dv * (a0 + BF_LO(sw)) + bb.x;
    float v1 = dv * (a1 + BF_HI(sw)) + bb.y;
    if (grp == 0) {
        float2 r; r.x = v0; r.y = v1;
        ((float2*)(out + (size_t)d * OUT_DIM))[fp] = r;
    }
}

// ---------------------------------------------------------------- launch
extern "C" void kernel_launch(void* const* d_in, const int* in_sizes, int n_in,
                              void* d_out, int out_size, void* d_ws, size_t ws_size,
                              hipStream_t stream) {
    const float* x  = (const float*)d_in[0];
    const int*   ei = (const int*)d_in[1];
    const float* W1 = (const float*)d_in[2];
    const float* b1 = (const float*)d_in[3];
    const float* W2 = (const float*)d_in[4];
    const float* b2 = (const float*)d_in[5];
    float* out = (float*)d_out;

    const int N = in_sizes[0] / IN_DIM;
    const int E = in_sizes[1] / 2;
    const int* src = ei;
    const int* dst = ei + E;

    const int B   = (N + BSIZE - 1) / BSIZE;
    const int nPB = (E + PEB - 1) / PEB;
    const int M   = B * nPB;
    const int nchunks = (M + 1023) / 1024;

    char* p = (char*)d_ws;
    auto alloc = [&](size_t bytes) -> void* {
        void* r = (void*)p;
        p += (bytes + 255) & ~(size_t)255;
        return r;
    };
    int*            mat    = (int*)alloc((size_t)M * 4);
    int*            mats   = (int*)alloc((size_t)M * 4);
    int*            sums   = (int*)alloc((size_t)nchunks * 4);
    unsigned*       packed = (unsigned*)alloc((size_t)E * 4);
    int*            colidx = (int*)alloc((size_t)E * 4);
    int*            rowptr = (int*)alloc((size_t)(N + 1) * 4);
    float*          dinv   = (float*)alloc((size_t)N * 4);
    unsigned*       g1b    = (unsigned*)alloc((size_t)N * 32 * 4);       // bf16x2 x 32/row
    unsigned short* g2b    = (unsigned short*)alloc((size_t)N * 32 * 2); // bf16 x 32/row

    k_hist<<<nPB, 256, 0, stream>>>(dst, E, mat, B, nPB);
    k_chunk_sums<<<nchunks, 256, 0, stream>>>(mat, M, sums);
    k_scan_sums<<<1, 1024, 0, stream>>>(sums, nchunks);
    k_scan_chunks<<<nchunks, 256, 0, stream>>>(mat, M, sums, mats);
    k_partition<<<nPB, 256, 0, stream>>>(src, dst, E, mats, packed, B, nPB);
    k_csrfill<<<B, 256, 0, stream>>>(packed, mats, colidx, rowptr, dinv, N, E, B, nPB);

    k_gemm1<<<(N + 63) / 64, 256, 0, stream>>>(x, W1, dinv, g1b, N);
    k_agg1f<<<(N + 3) / 4, 256, 0, stream>>>(g1b, rowptr, colidx, dinv, b1, W2,
                                             g2b, N);
    k_agg2<<<(N + 3) / 4, 256, 0, stream>>>((const unsigned*)g2b, rowptr, colidx,
                                            dinv, b2, out, N);
}

// Round 6
// 283.884 us; speedup vs baseline: 1.1246x; 1.0437x over previous
//
#include <hip/hip_runtime.h>
#include <hip/hip_bf16.h>

// 2-layer GCN (PyG GCNConv) on MI355X.
// R6: dwordx4 gather. Each lane loads uint4 = 16B of a bf16 row:
//   agg1: 8 lanes/row (128B) -> 8 edges per load instruction
//   agg2: 4 lanes/row (64B)  -> 16 edges per load instruction
// Quarters gather instruction count, 4x bytes-in-flight per vmcnt slot
// (latency x MLP bound per R5 counters: VALU 35%, HBM 15%, occ 77%).
//
// Pipeline: hist -> scan -> partition -> per-bucket CSR fill (+dinv) ->
//           gemm1 -> agg1f (gather + relu + @W2 * dinv -> g2b bf16) -> agg2.

#define IN_DIM 128
#define HID_DIM 64
#define OUT_DIM 32
#define BSHIFT 8
#define BSIZE 256
#define BMASK 255
#define PEB 8192   // edges per partition block

__device__ inline unsigned pack_bf16x2(float a, float b) {
    unsigned ua = __float_as_uint(a), ub = __float_as_uint(b);
    unsigned ra = (ua + 0x7fffu + ((ua >> 16) & 1u)) >> 16;        // RNE
    unsigned rb = (ub + 0x7fffu + ((ub >> 16) & 1u)) & 0xffff0000u;
    return (ra & 0xffffu) | rb;
}
__device__ inline unsigned short f2bf(float f) {
    unsigned u = __float_as_uint(f);
    return (unsigned short)((u + 0x7fffu + ((u >> 16) & 1u)) >> 16);
}
#define BF_LO(w) __uint_as_float((w) << 16)
#define BF_HI(w) __uint_as_float((w) & 0xffff0000u)

#define ACC8(q)                                         \
    do {                                                \
        acc[0] += BF_LO((q).x); acc[1] += BF_HI((q).x); \
        acc[2] += BF_LO((q).y); acc[3] += BF_HI((q).y); \
        acc[4] += BF_LO((q).z); acc[5] += BF_HI((q).z); \
        acc[6] += BF_LO((q).w); acc[7] += BF_HI((q).w); \
    } while (0)

// ---------------------------------------------------------------- pass 1: bucket histogram
__global__ __launch_bounds__(256) void k_hist(const int* __restrict__ dst, int E,
                                              int* __restrict__ mat, int B, int nPB) {
    __shared__ int cnt[512];
    int t = threadIdx.x;
    for (int b = t; b < B; b += 256) cnt[b] = 0;
    __syncthreads();
    int base = blockIdx.x * PEB;
#pragma unroll
    for (int i = 0; i < PEB / 256; ++i) {
        int e = base + i * 256 + t;
        if (e < E) atomicAdd(&cnt[dst[e] >> BSHIFT], 1);
    }
    __syncthreads();
    for (int b = t; b < B; b += 256) mat[b * nPB + blockIdx.x] = cnt[b];
}

// ---------------------------------------------------------------- scan (2-level)
__global__ void k_chunk_sums(const int* __restrict__ arr, int M, int* __restrict__ sums) {
    __shared__ int sdata[256];
    int t = threadIdx.x;
    int base = blockIdx.x * 1024 + t * 4;
    int s = 0;
#pragma unroll
    for (int i = 0; i < 4; ++i) {
        int idx = base + i;
        if (idx < M) s += arr[idx];
    }
    sdata[t] = s;
    __syncthreads();
    for (int off = 128; off > 0; off >>= 1) {
        if (t < off) sdata[t] += sdata[t + off];
        __syncthreads();
    }
    if (t == 0) sums[blockIdx.x] = sdata[0];
}

__global__ void k_scan_sums(int* __restrict__ sums, int nchunks) {
    __shared__ int buf[1024];
    int t = threadIdx.x;  // 1024 threads
    int v = (t < nchunks) ? sums[t] : 0;
    buf[t] = v;
    __syncthreads();
    for (int off = 1; off < 1024; off <<= 1) {
        int x = (t >= off) ? buf[t - off] : 0;
        __syncthreads();
        buf[t] += x;
        __syncthreads();
    }
    if (t < nchunks) sums[t] = buf[t] - v;  // exclusive
}

__global__ void k_scan_chunks(const int* __restrict__ arr, int M,
                              const int* __restrict__ sums, int* __restrict__ out) {
    __shared__ int tsum[256];
    int t = threadIdx.x;
    int idx0 = blockIdx.x * 1024 + t * 4;
    int v[4];
    int s = 0;
#pragma unroll
    for (int i = 0; i < 4; ++i) {
        int idx = idx0 + i;
        v[i] = (idx < M) ? arr[idx] : 0;
        s += v[i];
    }
    tsum[t] = s;
    __syncthreads();
    int mine = s;
    for (int off = 1; off < 256; off <<= 1) {
        int x = (t >= off) ? tsum[t - off] : 0;
        __syncthreads();
        tsum[t] += x;
        __syncthreads();
    }
    int run = tsum[t] - mine + sums[blockIdx.x];
#pragma unroll
    for (int i = 0; i < 4; ++i) {
        int idx = idx0 + i;
        if (idx < M) out[idx] = run;
        run += v[i];
    }
}

// ---------------------------------------------------------------- pass 2: partition
__global__ __launch_bounds__(256) void k_partition(const int* __restrict__ src,
                                                   const int* __restrict__ dst, int E,
                                                   const int* __restrict__ mats,
                                                   unsigned* __restrict__ packed,
                                                   int B, int nPB) {
    __shared__ int off[512];
    int t = threadIdx.x;
    for (int b = t; b < B; b += 256) off[b] = mats[b * nPB + blockIdx.x];
    __syncthreads();
    int base = blockIdx.x * PEB;
#pragma unroll
    for (int i = 0; i < PEB / 256; ++i) {
        int e = base + i * 256 + t;
        if (e < E) {
            int d = dst[e];
            int s = src[e];
            int slot = atomicAdd(&off[d >> BSHIFT], 1);
            packed[slot] = ((unsigned)s << BSHIFT) | (unsigned)(d & BMASK);
        }
    }
}

// ---------------------------------------------------------------- pass 3: per-bucket CSR build
__global__ __launch_bounds__(256) void k_csrfill(const unsigned* __restrict__ packed,
                                                 const int* __restrict__ mats,
                                                 int* __restrict__ colidx,
                                                 int* __restrict__ rowptr,
                                                 float* __restrict__ dinv,
                                                 int N, int E, int B, int nPB) {
    __shared__ int ldeg[256];
    __shared__ int lscan[256];
    __shared__ int sexc[256];
    __shared__ int lfill[256];
    int t = threadIdx.x, bkt = blockIdx.x;
    int base = mats[bkt * nPB];
    int end  = (bkt + 1 < B) ? mats[(bkt + 1) * nPB] : E;
    ldeg[t] = 0;
    __syncthreads();
    for (int e = base + t; e < end; e += 256)
        atomicAdd(&ldeg[packed[e] & BMASK], 1);
    __syncthreads();
    int v = ldeg[t];
    lscan[t] = v;
    __syncthreads();
    for (int off = 1; off < 256; off <<= 1) {
        int x = (t >= off) ? lscan[t - off] : 0;
        __syncthreads();
        lscan[t] += x;
        __syncthreads();
    }
    int exc = lscan[t] - v;
    sexc[t] = exc;
    lfill[t] = 0;
    int node = (bkt << BSHIFT) + t;
    if (node < N) {
        rowptr[node] = base + exc;
        dinv[node] = rsqrtf((float)v + 1.0f);
    }
    if (bkt == B - 1 && t == 0) rowptr[N] = E;
    __syncthreads();
    for (int e = base + t; e < end; e += 256) {
        unsigned w = packed[e];
        int ld = w & BMASK;
        int pos = base + sexc[ld] + atomicAdd(&lfill[ld], 1);
        colidx[pos] = (int)(w >> BSHIFT);
    }
}

// ---------------------------------------------------------------- GEMM1: g1b = bf16((x @ W1) * dinv)
__global__ __launch_bounds__(256) void k_gemm1(const float* __restrict__ x,
                                               const float* __restrict__ W,
                                               const float* __restrict__ dinv,
                                               unsigned* __restrict__ g1b, int N) {
    __shared__ float xs[64 * 128];
    __shared__ float ws[128 * 64];
    int t = threadIdx.x;
    int row0 = blockIdx.x * 64;

    const float4* W4 = (const float4*)W;
    float4* ws4 = (float4*)ws;
#pragma unroll
    for (int i = 0; i < 8; ++i) ws4[t + 256 * i] = W4[t + 256 * i];
#pragma unroll
    for (int i = 0; i < 8; ++i) {
        int l = t + 256 * i;
        int r = l >> 5;
        int c4 = l & 31;
        int row = row0 + r;
        float4 val = make_float4(0.f, 0.f, 0.f, 0.f);
        if (row < N) val = ((const float4*)(x + (size_t)row * IN_DIM))[c4];
        *(float4*)&xs[r * IN_DIM + c4 * 4] = val;
    }
    __syncthreads();

    int tx = t & 15;
    int ty = t >> 4;
    float acc[4][4] = {};
    for (int k = 0; k < 128; k += 4) {
        float a[4][4], b[4][4];
#pragma unroll
        for (int i = 0; i < 4; ++i)
            *(float4*)a[i] = *(const float4*)&xs[(ty * 4 + i) * IN_DIM + k];
#pragma unroll
        for (int kk = 0; kk < 4; ++kk)
            *(float4*)b[kk] = *(const float4*)&ws[(k + kk) * HID_DIM + tx * 4];
#pragma unroll
        for (int i = 0; i < 4; ++i)
#pragma unroll
            for (int kk = 0; kk < 4; ++kk)
#pragma unroll
                for (int j = 0; j < 4; ++j)
                    acc[i][j] += a[i][kk] * b[kk][j];
    }
#pragma unroll
    for (int i = 0; i < 4; ++i) {
        int row = row0 + ty * 4 + i;
        if (row < N) {
            float dv = dinv[row];
            uint2 u;
            u.x = pack_bf16x2(acc[i][0] * dv, acc[i][1] * dv);
            u.y = pack_bf16x2(acc[i][2] * dv, acc[i][3] * dv);
            *(uint2*)&g1b[(size_t)row * 32 + tx * 2] = u;
        }
    }
}

// ---------------------------------------------------------------- agg1 + fused GEMM2
// One wave per node. Gather: lane = (grp 0..7, fp 0..7); lane loads uint4 =
// 16B, 8 lanes cover one 128B row -> 8 edges per load inst, 2 insts/iter =
// 16 edges in flight. Combine via shfl_xor(8,16,32) over 8 accumulators.
// Epilogue: relu row -> per-wave LDS buffer -> fused @W2 (j = lane&31 half-dot
// + shfl_xor(32)), scale by dinv, pack bf16 -> g2b.
__global__ __launch_bounds__(256) void k_agg1f(const unsigned* __restrict__ g1,
                                               const int* __restrict__ rowptr,
                                               const int* __restrict__ colidx,
                                               const float* __restrict__ dinv,
                                               const float* __restrict__ b1,
                                               const float* __restrict__ W2,
                                               unsigned short* __restrict__ g2b, int N) {
    __shared__ float W2s[HID_DIM * OUT_DIM];  // 8KB, [k][j]
    __shared__ float rowb[4][HID_DIM];        // per-wave relu row
    int t = threadIdx.x;
#pragma unroll
    for (int i = 0; i < 8; ++i) W2s[t + 256 * i] = W2[t + 256 * i];
    __syncthreads();

    int dd = (blockIdx.x * 256 + t) >> 6;
    bool live = dd < N;
    int d = live ? dd : N - 1;
    int lane = t & 63, grp = lane >> 3, fp = lane & 7, w = t >> 6;

    float acc[8] = {};
    int beg = rowptr[d], end = rowptr[d + 1];
    int e = beg;
    for (; e + 16 <= end; e += 16) {
        int s0 = colidx[e + grp];
        int s1 = colidx[e + 8 + grp];
        uint4 q0 = *(const uint4*)&g1[(size_t)s0 * 32 + fp * 4];
        uint4 q1 = *(const uint4*)&g1[(size_t)s1 * 32 + fp * 4];
        ACC8(q0);
        ACC8(q1);
    }
    for (; e + 8 <= end; e += 8) {
        int s = colidx[e + grp];
        uint4 q = *(const uint4*)&g1[(size_t)s * 32 + fp * 4];
        ACC8(q);
    }
    if (e < end) {  // 1..7 edges left
        int cnt = end - e;
        int s = colidx[(grp < cnt) ? e + grp : e];
        uint4 q = *(const uint4*)&g1[(size_t)s * 32 + fp * 4];
        if (grp < cnt) ACC8(q);
    }
#pragma unroll
    for (int i = 0; i < 8; ++i) {
        acc[i] += __shfl_xor(acc[i], 8);
        acc[i] += __shfl_xor(acc[i], 16);
        acc[i] += __shfl_xor(acc[i], 32);
    }

    // self-loop (all lanes add identical value -> stays consistent)
    uint4 sq = *(const uint4*)&g1[(size_t)d * 32 + fp * 4];
    ACC8(sq);
    float dv = dinv[d];
    float4 bb0 = ((const float4*)b1)[fp * 2];
    float4 bb1 = ((const float4*)b1)[fp * 2 + 1];
    float v0 = dv * acc[0] + bb0.x, v1 = dv * acc[1] + bb0.y;
    float v2 = dv * acc[2] + bb0.z, v3 = dv * acc[3] + bb0.w;
    float v4 = dv * acc[4] + bb1.x, v5 = dv * acc[5] + bb1.y;
    float v6 = dv * acc[6] + bb1.z, v7 = dv * acc[7] + bb1.w;
    if (grp == 0) {
        float4 r0, r1;
        r0.x = v0 > 0.f ? v0 : 0.f; r0.y = v1 > 0.f ? v1 : 0.f;
        r0.z = v2 > 0.f ? v2 : 0.f; r0.w = v3 > 0.f ? v3 : 0.f;
        r1.x = v4 > 0.f ? v4 : 0.f; r1.y = v5 > 0.f ? v5 : 0.f;
        r1.z = v6 > 0.f ? v6 : 0.f; r1.w = v7 > 0.f ? v7 : 0.f;
        *(float4*)&rowb[w][fp * 8] = r0;
        *(float4*)&rowb[w][fp * 8 + 4] = r1;
    }
    __syncthreads();

    // fused GEMM2: out feat j = lane&31, half h = lane>>5 covers k in [32h,32h+32)
    int j = lane & 31, h = lane >> 5;
    float a2 = 0.f;
#pragma unroll
    for (int k = 0; k < 32; ++k) {
        float rv = rowb[w][h * 32 + k];            // broadcast within half
        a2 += rv * W2s[(h * 32 + k) * OUT_DIM + j];
    }
    a2 += __shfl_xor(a2, 32);
    if (live && h == 0)
        g2b[(size_t)dd * 32 + j] = f2bf(a2 * dv);
}

// ---------------------------------------------------------------- agg layer 2
// One wave per node. lane = (grp 0..15, fp 0..3); lane loads uint4 = 16B,
// 4 lanes cover one 64B row -> 16 edges per load instruction.
// Combine via shfl_xor(4,8,16,32).
__global__ __launch_bounds__(256) void k_agg2(const unsigned* __restrict__ g2,
                                              const int* __restrict__ rowptr,
                                              const int* __restrict__ colidx,
                                              const float* __restrict__ dinv,
                                              const float* __restrict__ b2,
                                              float* __restrict__ out, int N) {
    int d = (blockIdx.x * 256 + threadIdx.x) >> 6;
    if (d >= N) return;
    int lane = threadIdx.x & 63;
    int grp = lane >> 2, fp = lane & 3;
    float acc[8] = {};
    int beg = rowptr[d], end = rowptr[d + 1];
    int e = beg;
    for (; e + 32 <= end; e += 32) {
        int s0 = colidx[e + grp];
        int s1 = colidx[e + 16 + grp];
        uint4 q0 = *(const uint4*)&g2[(size_t)s0 * 16 + fp * 4];
        uint4 q1 = *(const uint4*)&g2[(size_t)s1 * 16 + fp * 4];
        ACC8(q0);
        ACC8(q1);
    }
    for (; e + 16 <= end; e += 16) {
        int s = colidx[e + grp];
        uint4 q = *(const uint4*)&g2[(size_t)s * 16 + fp * 4];
        ACC8(q);
    }
    if (e < end) {  // 1..15 edges left
        int cnt = end - e;
        int s = colidx[(grp < cnt) ? e + grp : e];
        uint4 q = *(const uint4*)&g2[(size_t)s * 16 + fp * 4];
        if (grp < cnt) ACC8(q);
    }
#pragma unroll
    for (int i = 0; i < 8; ++i) {
        acc[i] += __shfl_xor(acc[i], 4);
        acc[i] += __shfl_xor(acc[i], 8);
        acc[i] += __shfl_xor(acc[i], 16);
        acc[i] += __shfl_xor(acc[i], 32);
    }
    // self-loop
    uint4 sq = *(const uint4*)&g2[(size_t)d * 16 + fp * 4];
    ACC8(sq);
    float dv = dinv[d];
    float4 bb0 = ((const float4*)b2)[fp * 2];
    float4 bb1 = ((const float4*)b2)[fp * 2 + 1];
    if (grp == 0) {
        float4 r0, r1;
        r0.x = dv * acc[0] + bb0.x; r0.y = dv * acc[1] + bb0.y;
        r0.z = dv * acc[2] + bb0.z; r0.w = dv * acc[3] + bb0.w;
        r1.x = dv * acc[4] + bb1.x; r1.y = dv * acc[5] + bb1.y;
        r1.z = dv * acc[6] + bb1.z; r1.w = dv * acc[7] + bb1.w;
        *(float4*)&out[(size_t)d * OUT_DIM + fp * 8] = r0;
        *(float4*)&out[(size_t)d * OUT_DIM + fp * 8 + 4] = r1;
    }
}

// ---------------------------------------------------------------- launch
extern "C" void kernel_launch(void* const* d_in, const int* in_sizes, int n_in,
                              void* d_out, int out_size, void* d_ws, size_t ws_size,
                              hipStream_t stream) {
    const float* x  = (const float*)d_in[0];
    const int*   ei = (const int*)d_in[1];
    const float* W1 = (const float*)d_in[2];
    const float* b1 = (const float*)d_in[3];
    const float* W2 = (const float*)d_in[4];
    const float* b2 = (const float*)d_in[5];
    float* out = (float*)d_out;

    const int N = in_sizes[0] / IN_DIM;
    const int E = in_sizes[1] / 2;
    const int* src = ei;
    const int* dst = ei + E;

    const int B   = (N + BSIZE - 1) / BSIZE;
    const int nPB = (E + PEB - 1) / PEB;
    const int M   = B * nPB;
    const int nchunks = (M + 1023) / 1024;

    char* p = (char*)d_ws;
    auto alloc = [&](size_t bytes) -> void* {
        void* r = (void*)p;
        p += (bytes + 255) & ~(size_t)255;
        return r;
    };
    int*            mat    = (int*)alloc((size_t)M * 4);
    int*            mats   = (int*)alloc((size_t)M * 4);
    int*            sums   = (int*)alloc((size_t)nchunks * 4);
    unsigned*       packed = (unsigned*)alloc((size_t)E * 4);
    int*            colidx = (int*)alloc((size_t)E * 4);
    int*            rowptr = (int*)alloc((size_t)(N + 1) * 4);
    float*          dinv   = (float*)alloc((size_t)N * 4);
    unsigned*       g1b    = (unsigned*)alloc((size_t)N * 32 * 4);       // bf16x2 x 32/row
    unsigned short* g2b    = (unsigned short*)alloc((size_t)N * 32 * 2); // bf16 x 32/row

    k_hist<<<nPB, 256, 0, stream>>>(dst, E, mat, B, nPB);
    k_chunk_sums<<<nchunks, 256, 0, stream>>>(mat, M, sums);
    k_scan_sums<<<1, 1024, 0, stream>>>(sums, nchunks);
    k_scan_chunks<<<nchunks, 256, 0, stream>>>(mat, M, sums, mats);
    k_partition<<<nPB, 256, 0, stream>>>(src, dst, E, mats, packed, B, nPB);
    k_csrfill<<<B, 256, 0, stream>>>(packed, mats, colidx, rowptr, dinv, N, E, B, nPB);

    k_gemm1<<<(N + 63) / 64, 256, 0, stream>>>(x, W1, dinv, g1b, N);
    k_agg1f<<<(N + 3) / 4, 256, 0, stream>>>(g1b, rowptr, colidx, dinv, b1, W2,
                                             g2b, N);
    k_agg2<<<(N + 3) / 4, 256, 0, stream>>>((const unsigned*)g2b, rowptr, colidx,
                                            dinv, b2, out, N);
}

// Round 7
// 277.819 us; speedup vs baseline: 1.1491x; 1.0218x over previous
//
#include <hip/hip_runtime.h>
#include <hip/hip_bf16.h>

// 2-layer GCN (PyG GCNConv) on MI355X.
// R7: barrier-free, LDS-free agg1f epilogue.
//   - W2 column slice preloaded into 32 VGPRs/lane (global loads overlap the
//     gather's vmcnt waits) -> kills 32 ds_read_b32/W2s per node.
//   - Row broadcast via ds_bpermute (__shfl with per-lane src) instead of a
//     rowb LDS round-trip -> kills the block __syncthreads straggler coupling
//     (R6: 200k bank conflicts, epilogue ~= gather cost).
//
// Pipeline: hist -> scan -> partition -> per-bucket CSR fill (+dinv) ->
//           gemm1 -> agg1f (gather + relu + @W2 * dinv -> g2b bf16) -> agg2.

#define IN_DIM 128
#define HID_DIM 64
#define OUT_DIM 32
#define BSHIFT 8
#define BSIZE 256
#define BMASK 255
#define PEB 8192   // edges per partition block

__device__ inline unsigned pack_bf16x2(float a, float b) {
    unsigned ua = __float_as_uint(a), ub = __float_as_uint(b);
    unsigned ra = (ua + 0x7fffu + ((ua >> 16) & 1u)) >> 16;        // RNE
    unsigned rb = (ub + 0x7fffu + ((ub >> 16) & 1u)) & 0xffff0000u;
    return (ra & 0xffffu) | rb;
}
__device__ inline unsigned short f2bf(float f) {
    unsigned u = __float_as_uint(f);
    return (unsigned short)((u + 0x7fffu + ((u >> 16) & 1u)) >> 16);
}
#define BF_LO(w) __uint_as_float((w) << 16)
#define BF_HI(w) __uint_as_float((w) & 0xffff0000u)

#define ACC8(q)                                         \
    do {                                                \
        acc[0] += BF_LO((q).x); acc[1] += BF_HI((q).x); \
        acc[2] += BF_LO((q).y); acc[3] += BF_HI((q).y); \
        acc[4] += BF_LO((q).z); acc[5] += BF_HI((q).z); \
        acc[6] += BF_LO((q).w); acc[7] += BF_HI((q).w); \
    } while (0)

// ---------------------------------------------------------------- pass 1: bucket histogram
__global__ __launch_bounds__(256) void k_hist(const int* __restrict__ dst, int E,
                                              int* __restrict__ mat, int B, int nPB) {
    __shared__ int cnt[512];
    int t = threadIdx.x;
    for (int b = t; b < B; b += 256) cnt[b] = 0;
    __syncthreads();
    int base = blockIdx.x * PEB;
#pragma unroll
    for (int i = 0; i < PEB / 256; ++i) {
        int e = base + i * 256 + t;
        if (e < E) atomicAdd(&cnt[dst[e] >> BSHIFT], 1);
    }
    __syncthreads();
    for (int b = t; b < B; b += 256) mat[b * nPB + blockIdx.x] = cnt[b];
}

// ---------------------------------------------------------------- scan (2-level)
__global__ void k_chunk_sums(const int* __restrict__ arr, int M, int* __restrict__ sums) {
    __shared__ int sdata[256];
    int t = threadIdx.x;
    int base = blockIdx.x * 1024 + t * 4;
    int s = 0;
#pragma unroll
    for (int i = 0; i < 4; ++i) {
        int idx = base + i;
        if (idx < M) s += arr[idx];
    }
    sdata[t] = s;
    __syncthreads();
    for (int off = 128; off > 0; off >>= 1) {
        if (t < off) sdata[t] += sdata[t + off];
        __syncthreads();
    }
    if (t == 0) sums[blockIdx.x] = sdata[0];
}

__global__ void k_scan_sums(int* __restrict__ sums, int nchunks) {
    __shared__ int buf[1024];
    int t = threadIdx.x;  // 1024 threads
    int v = (t < nchunks) ? sums[t] : 0;
    buf[t] = v;
    __syncthreads();
    for (int off = 1; off < 1024; off <<= 1) {
        int x = (t >= off) ? buf[t - off] : 0;
        __syncthreads();
        buf[t] += x;
        __syncthreads();
    }
    if (t < nchunks) sums[t] = buf[t] - v;  // exclusive
}

__global__ void k_scan_chunks(const int* __restrict__ arr, int M,
                              const int* __restrict__ sums, int* __restrict__ out) {
    __shared__ int tsum[256];
    int t = threadIdx.x;
    int idx0 = blockIdx.x * 1024 + t * 4;
    int v[4];
    int s = 0;
#pragma unroll
    for (int i = 0; i < 4; ++i) {
        int idx = idx0 + i;
        v[i] = (idx < M) ? arr[idx] : 0;
        s += v[i];
    }
    tsum[t] = s;
    __syncthreads();
    int mine = s;
    for (int off = 1; off < 256; off <<= 1) {
        int x = (t >= off) ? tsum[t - off] : 0;
        __syncthreads();
        tsum[t] += x;
        __syncthreads();
    }
    int run = tsum[t] - mine + sums[blockIdx.x];
#pragma unroll
    for (int i = 0; i < 4; ++i) {
        int idx = idx0 + i;
        if (idx < M) out[idx] = run;
        run += v[i];
    }
}

// ---------------------------------------------------------------- pass 2: partition
__global__ __launch_bounds__(256) void k_partition(const int* __restrict__ src,
                                                   const int* __restrict__ dst, int E,
                                                   const int* __restrict__ mats,
                                                   unsigned* __restrict__ packed,
                                                   int B, int nPB) {
    __shared__ int off[512];
    int t = threadIdx.x;
    for (int b = t; b < B; b += 256) off[b] = mats[b * nPB + blockIdx.x];
    __syncthreads();
    int base = blockIdx.x * PEB;
#pragma unroll
    for (int i = 0; i < PEB / 256; ++i) {
        int e = base + i * 256 + t;
        if (e < E) {
            int d = dst[e];
            int s = src[e];
            int slot = atomicAdd(&off[d >> BSHIFT], 1);
            packed[slot] = ((unsigned)s << BSHIFT) | (unsigned)(d & BMASK);
        }
    }
}

// ---------------------------------------------------------------- pass 3: per-bucket CSR build
__global__ __launch_bounds__(256) void k_csrfill(const unsigned* __restrict__ packed,
                                                 const int* __restrict__ mats,
                                                 int* __restrict__ colidx,
                                                 int* __restrict__ rowptr,
                                                 float* __restrict__ dinv,
                                                 int N, int E, int B, int nPB) {
    __shared__ int ldeg[256];
    __shared__ int lscan[256];
    __shared__ int sexc[256];
    __shared__ int lfill[256];
    int t = threadIdx.x, bkt = blockIdx.x;
    int base = mats[bkt * nPB];
    int end  = (bkt + 1 < B) ? mats[(bkt + 1) * nPB] : E;
    ldeg[t] = 0;
    __syncthreads();
    for (int e = base + t; e < end; e += 256)
        atomicAdd(&ldeg[packed[e] & BMASK], 1);
    __syncthreads();
    int v = ldeg[t];
    lscan[t] = v;
    __syncthreads();
    for (int off = 1; off < 256; off <<= 1) {
        int x = (t >= off) ? lscan[t - off] : 0;
        __syncthreads();
        lscan[t] += x;
        __syncthreads();
    }
    int exc = lscan[t] - v;
    sexc[t] = exc;
    lfill[t] = 0;
    int node = (bkt << BSHIFT) + t;
    if (node < N) {
        rowptr[node] = base + exc;
        dinv[node] = rsqrtf((float)v + 1.0f);
    }
    if (bkt == B - 1 && t == 0) rowptr[N] = E;
    __syncthreads();
    for (int e = base + t; e < end; e += 256) {
        unsigned w = packed[e];
        int ld = w & BMASK;
        int pos = base + sexc[ld] + atomicAdd(&lfill[ld], 1);
        colidx[pos] = (int)(w >> BSHIFT);
    }
}

// ---------------------------------------------------------------- GEMM1: g1b = bf16((x @ W1) * dinv)
__global__ __launch_bounds__(256) void k_gemm1(const float* __restrict__ x,
                                               const float* __restrict__ W,
                                               const float* __restrict__ dinv,
                                               unsigned* __restrict__ g1b, int N) {
    __shared__ float xs[64 * 128];
    __shared__ float ws[128 * 64];
    int t = threadIdx.x;
    int row0 = blockIdx.x * 64;

    const float4* W4 = (const float4*)W;
    float4* ws4 = (float4*)ws;
#pragma unroll
    for (int i = 0; i < 8; ++i) ws4[t + 256 * i] = W4[t + 256 * i];
#pragma unroll
    for (int i = 0; i < 8; ++i) {
        int l = t + 256 * i;
        int r = l >> 5;
        int c4 = l & 31;
        int row = row0 + r;
        float4 val = make_float4(0.f, 0.f, 0.f, 0.f);
        if (row < N) val = ((const float4*)(x + (size_t)row * IN_DIM))[c4];
        *(float4*)&xs[r * IN_DIM + c4 * 4] = val;
    }
    __syncthreads();

    int tx = t & 15;
    int ty = t >> 4;
    float acc[4][4] = {};
    for (int k = 0; k < 128; k += 4) {
        float a[4][4], b[4][4];
#pragma unroll
        for (int i = 0; i < 4; ++i)
            *(float4*)a[i] = *(const float4*)&xs[(ty * 4 + i) * IN_DIM + k];
#pragma unroll
        for (int kk = 0; kk < 4; ++kk)
            *(float4*)b[kk] = *(const float4*)&ws[(k + kk) * HID_DIM + tx * 4];
#pragma unroll
        for (int i = 0; i < 4; ++i)
#pragma unroll
            for (int kk = 0; kk < 4; ++kk)
#pragma unroll
                for (int j = 0; j < 4; ++j)
                    acc[i][j] += a[i][kk] * b[kk][j];
    }
#pragma unroll
    for (int i = 0; i < 4; ++i) {
        int row = row0 + ty * 4 + i;
        if (row < N) {
            float dv = dinv[row];
            uint2 u;
            u.x = pack_bf16x2(acc[i][0] * dv, acc[i][1] * dv);
            u.y = pack_bf16x2(acc[i][2] * dv, acc[i][3] * dv);
            *(uint2*)&g1b[(size_t)row * 32 + tx * 2] = u;
        }
    }
}

// ---------------------------------------------------------------- agg1 + fused GEMM2
// One wave per node, NO LDS, NO barriers.
// Gather: lane = (grp 0..7, fp 0..7); lane loads uint4 = 16B, 8 lanes/row ->
// 8 edges per load inst, 2 insts/iter = 16 edges in flight.
// W2 column slice (32 floats: W2[32h+m][j], j=lane&31, h=lane>>5) preloaded
// into VGPRs before the gather; loads hide under gather latency.
// Epilogue: xor-reduce -> all lanes hold full row (8x replicated) -> relu on
// all lanes -> 32 x (bpermute + fma) -> shfl_xor(32) -> g2b bf16.
__global__ __launch_bounds__(256) void k_agg1f(const unsigned* __restrict__ g1,
                                               const int* __restrict__ rowptr,
                                               const int* __restrict__ colidx,
                                               const float* __restrict__ dinv,
                                               const float* __restrict__ b1,
                                               const float* __restrict__ W2,
                                               unsigned short* __restrict__ g2b, int N) {
    int t = threadIdx.x;
    int dd = (blockIdx.x * 256 + t) >> 6;
    bool live = dd < N;
    int d = live ? dd : N - 1;
    int lane = t & 63, grp = lane >> 3, fp = lane & 7;
    int j = lane & 31, h = lane >> 5;

    // preload W2 slice: w2r[m] = W2[(32h+m)*32 + j]  (coalesced in j, L2-hot)
    float w2r[32];
#pragma unroll
    for (int m = 0; m < 32; ++m)
        w2r[m] = W2[(size_t)(h * 32 + m) * OUT_DIM + j];

    float acc[8] = {};
    int beg = rowptr[d], end = rowptr[d + 1];
    int e = beg;
    for (; e + 16 <= end; e += 16) {
        int s0 = colidx[e + grp];
        int s1 = colidx[e + 8 + grp];
        uint4 q0 = *(const uint4*)&g1[(size_t)s0 * 32 + fp * 4];
        uint4 q1 = *(const uint4*)&g1[(size_t)s1 * 32 + fp * 4];
        ACC8(q0);
        ACC8(q1);
    }
    for (; e + 8 <= end; e += 8) {
        int s = colidx[e + grp];
        uint4 q = *(const uint4*)&g1[(size_t)s * 32 + fp * 4];
        ACC8(q);
    }
    if (e < end) {  // 1..7 edges left
        int cnt = end - e;
        int s = colidx[(grp < cnt) ? e + grp : e];
        uint4 q = *(const uint4*)&g1[(size_t)s * 32 + fp * 4];
        if (grp < cnt) ACC8(q);
    }
#pragma unroll
    for (int i = 0; i < 8; ++i) {
        acc[i] += __shfl_xor(acc[i], 8);
        acc[i] += __shfl_xor(acc[i], 16);
        acc[i] += __shfl_xor(acc[i], 32);
    }

    // self-loop + scale + bias + relu, on ALL lanes (row replicated 8x)
    uint4 sq = *(const uint4*)&g1[(size_t)d * 32 + fp * 4];
    ACC8(sq);
    float dv = dinv[d];
    float4 bb0 = ((const float4*)b1)[fp * 2];
    float4 bb1 = ((const float4*)b1)[fp * 2 + 1];
    acc[0] = fmaxf(dv * acc[0] + bb0.x, 0.f);
    acc[1] = fmaxf(dv * acc[1] + bb0.y, 0.f);
    acc[2] = fmaxf(dv * acc[2] + bb0.z, 0.f);
    acc[3] = fmaxf(dv * acc[3] + bb0.w, 0.f);
    acc[4] = fmaxf(dv * acc[4] + bb1.x, 0.f);
    acc[5] = fmaxf(dv * acc[5] + bb1.y, 0.f);
    acc[6] = fmaxf(dv * acc[6] + bb1.z, 0.f);
    acc[7] = fmaxf(dv * acc[7] + bb1.w, 0.f);

    // fused GEMM2: lane (j,h) accumulates k = 32h+m over m=0..31.
    // row[32h+m] lives (replicated) in acc[m&7] of lanes with fp = 4h+(m>>3);
    // per-lane src => ds_bpermute via __shfl.
    float a2 = 0.f;
    int srcbase = h << 2;
#pragma unroll
    for (int m = 0; m < 32; ++m) {
        float rv = __shfl(acc[m & 7], srcbase + (m >> 3), 64);
        a2 += rv * w2r[m];
    }
    a2 += __shfl_xor(a2, 32);
    if (live && h == 0)
        g2b[(size_t)dd * 32 + j] = f2bf(a2 * dv);
}

// ---------------------------------------------------------------- agg layer 2
// One wave per node. lane = (grp 0..15, fp 0..3); lane loads uint4 = 16B,
// 4 lanes cover one 64B row -> 16 edges per load instruction.
__global__ __launch_bounds__(256) void k_agg2(const unsigned* __restrict__ g2,
                                              const int* __restrict__ rowptr,
                                              const int* __restrict__ colidx,
                                              const float* __restrict__ dinv,
                                              const float* __restrict__ b2,
                                              float* __restrict__ out, int N) {
    int d = (blockIdx.x * 256 + threadIdx.x) >> 6;
    if (d >= N) return;
    int lane = threadIdx.x & 63;
    int grp = lane >> 2, fp = lane & 3;
    float acc[8] = {};
    int beg = rowptr[d], end = rowptr[d + 1];
    int e = beg;
    for (; e + 32 <= end; e += 32) {
        int s0 = colidx[e + grp];
        int s1 = colidx[e + 16 + grp];
        uint4 q0 = *(const uint4*)&g2[(size_t)s0 * 16 + fp * 4];
        uint4 q1 = *(const uint4*)&g2[(size_t)s1 * 16 + fp * 4];
        ACC8(q0);
        ACC8(q1);
    }
    for (; e + 16 <= end; e += 16) {
        int s = colidx[e + grp];
        uint4 q = *(const uint4*)&g2[(size_t)s * 16 + fp * 4];
        ACC8(q);
    }
    if (e < end) {  // 1..15 edges left
        int cnt = end - e;
        int s = colidx[(grp < cnt) ? e + grp : e];
        uint4 q = *(const uint4*)&g2[(size_t)s * 16 + fp * 4];
        if (grp < cnt) ACC8(q);
    }
#pragma unroll
    for (int i = 0; i < 8; ++i) {
        acc[i] += __shfl_xor(acc[i], 4);
        acc[i] += __shfl_xor(acc[i], 8);
        acc[i] += __shfl_xor(acc[i], 16);
        acc[i] += __shfl_xor(acc[i], 32);
    }
    // self-loop
    uint4 sq = *(const uint4*)&g2[(size_t)d * 16 + fp * 4];
    ACC8(sq);
    float dv = dinv[d];
    float4 bb0 = ((const float4*)b2)[fp * 2];
    float4 bb1 = ((const float4*)b2)[fp * 2 + 1];
    if (grp == 0) {
        float4 r0, r1;
        r0.x = dv * acc[0] + bb0.x; r0.y = dv * acc[1] + bb0.y;
        r0.z = dv * acc[2] + bb0.z; r0.w = dv * acc[3] + bb0.w;
        r1.x = dv * acc[4] + bb1.x; r1.y = dv * acc[5] + bb1.y;
        r1.z = dv * acc[6] + bb1.z; r1.w = dv * acc[7] + bb1.w;
        *(float4*)&out[(size_t)d * OUT_DIM + fp * 8] = r0;
        *(float4*)&out[(size_t)d * OUT_DIM + fp * 8 + 4] = r1;
    }
}

// ---------------------------------------------------------------- launch
extern "C" void kernel_launch(void* const* d_in, const int* in_sizes, int n_in,
                              void* d_out, int out_size, void* d_ws, size_t ws_size,
                              hipStream_t stream) {
    const float* x  = (const float*)d_in[0];
    const int*   ei = (const int*)d_in[1];
    const float* W1 = (const float*)d_in[2];
    const float* b1 = (const float*)d_in[3];
    const float* W2 = (const float*)d_in[4];
    const float* b2 = (const float*)d_in[5];
    float* out = (float*)d_out;

    const int N = in_sizes[0] / IN_DIM;
    const int E = in_sizes[1] / 2;
    const int* src = ei;
    const int* dst = ei + E;

    const int B   = (N + BSIZE - 1) / BSIZE;
    const int nPB = (E + PEB - 1) / PEB;
    const int M   = B * nPB;
    const int nchunks = (M + 1023) / 1024;

    char* p = (char*)d_ws;
    auto alloc = [&](size_t bytes) -> void* {
        void* r = (void*)p;
        p += (bytes + 255) & ~(size_t)255;
        return r;
    };
    int*            mat    = (int*)alloc((size_t)M * 4);
    int*            mats   = (int*)alloc((size_t)M * 4);
    int*            sums   = (int*)alloc((size_t)nchunks * 4);
    unsigned*       packed = (unsigned*)alloc((size_t)E * 4);
    int*            colidx = (int*)alloc((size_t)E * 4);
    int*            rowptr = (int*)alloc((size_t)(N + 1) * 4);
    float*          dinv   = (float*)alloc((size_t)N * 4);
    unsigned*       g1b    = (unsigned*)alloc((size_t)N * 32 * 4);       // bf16x2 x 32/row
    unsigned short* g2b    = (unsigned short*)alloc((size_t)N * 32 * 2); // bf16 x 32/row

    k_hist<<<nPB, 256, 0, stream>>>(dst, E, mat, B, nPB);
    k_chunk_sums<<<nchunks, 256, 0, stream>>>(mat, M, sums);
    k_scan_sums<<<1, 1024, 0, stream>>>(sums, nchunks);
    k_scan_chunks<<<nchunks, 256, 0, stream>>>(mat, M, sums, mats);
    k_partition<<<nPB, 256, 0, stream>>>(src, dst, E, mats, packed, B, nPB);
    k_csrfill<<<B, 256, 0, stream>>>(packed, mats, colidx, rowptr, dinv, N, E, B, nPB);

    k_gemm1<<<(N + 63) / 64, 256, 0, stream>>>(x, W1, dinv, g1b, N);
    k_agg1f<<<(N + 3) / 4, 256, 0, stream>>>(g1b, rowptr, colidx, dinv, b1, W2,
                                             g2b, N);
    k_agg2<<<(N + 3) / 4, 256, 0, stream>>>((const unsigned*)g2b, rowptr, colidx,
                                            dinv, b2, out, N);
}